// Round 3
// baseline (427.769 us; speedup 1.0000x reference)
//
#include <hip/hip_runtime.h>
#include <hip/hip_fp16.h>

// SSIM loss, fused, R3.
// R2 post-mortem: latency-bound (occ 21.6%, VALUBusy 43%, LDS conflicts 9M).
// R3: no raw LDS tile (h-pass reads global directly, L1-cached overlapping
// float4 windows); 5 h-intermediate arrays in fp16 (30.2KB LDS -> 4 blocks/CU);
// v-pass 4x4 px/thread reads each h-row once (4.4 b64/px); single barrier.

constexpr int IMG_H = 512;
constexpr int IMG_W = 512;
constexpr int NBC   = 48;             // B*C planes
constexpr int TW    = 64;             // output tile width
constexpr int TH    = 32;             // output tile height
constexpr int HALO  = 5;
constexpr int NTAP  = 11;
constexpr int IH    = TH + 2*HALO;    // 42 h-rows
constexpr int SH    = TW + 8;         // 72 halves: h-row stride (bank-uniform, b64-aligned)
constexpr int NBLKX = IMG_W / TW;     // 8
constexpr int NBLKY = IMG_H / TH;     // 16
constexpr int NBLK  = NBLKX * NBLKY * NBC; // 6144
constexpr float C1 = 1.0e-4f;
constexpr float C2 = 9.0e-4f;

__device__ __forceinline__ void make_weights(float* g) {
    float gsum = 0.f;
#pragma unroll
    for (int i = 0; i < NTAP; ++i) {
        float d = (float)(i - HALO);
        g[i] = expf(-d * d / (2.0f * 1.5f * 1.5f));
        gsum += g[i];
    }
#pragma unroll
    for (int i = 0; i < NTAP; ++i) g[i] /= gsum;
}

__global__ __launch_bounds__(64) void ssim_init(double* acc) {
    if (threadIdx.x == 0) acc[0] = 0.0;
}

__global__ __launch_bounds__(256, 4) void ssim_main(const float* __restrict__ sr,
                                                    const float* __restrict__ hr,
                                                    double* __restrict__ sink,
                                                    int mode) {
    __shared__ __half h1 [IH * SH];
    __shared__ __half h2 [IH * SH];
    __shared__ __half h11[IH * SH];
    __shared__ __half h22[IH * SH];
    __shared__ __half h12[IH * SH];
    __shared__ float wsums[4];

    float g[NTAP];
    make_weights(g);

    const int bc      = blockIdx.z;
    const int gr0     = blockIdx.y * TH - HALO;  // global row of h-row 0
    const int gc_base = blockIdx.x * TW;         // global col of output col 0
    const float* __restrict__ srp = sr + (size_t)bc * IMG_H * IMG_W;
    const float* __restrict__ hrp = hr + (size_t)bc * IMG_H * IMG_W;

    // ---- horizontal pass: task = 1 h-row x 4 output cols, direct global reads ----
    for (int tt = threadIdx.x; tt < IH * (TW / 4); tt += 256) { // 42*16 = 672
        const int r  = tt >> 4;
        const int cg = tt & 15;
        const int gr = gr0 + r;
        const int W0 = gc_base + cg * 4;         // first output col of this task
        float A[20], B[20];                      // global cols W0-8 .. W0+11
        if ((unsigned)gr < (unsigned)IMG_H) {
            const float* __restrict__ ra = srp + (size_t)gr * IMG_W;
            const float* __restrict__ rb = hrp + (size_t)gr * IMG_W;
            if (W0 >= 8 && W0 <= 500) {          // fully interior: 5 aligned float4
#pragma unroll
                for (int s = 0; s < 5; ++s) {
                    *(float4*)&A[4*s] = *(const float4*)&ra[W0 - 8 + 4*s];
                    *(float4*)&B[4*s] = *(const float4*)&rb[W0 - 8 + 4*s];
                }
            } else {                             // image-edge columns: guarded scalar
#pragma unroll
                for (int i = 0; i < 20; ++i) {
                    const int c = W0 - 8 + i;
                    const bool ok = (unsigned)c < (unsigned)IMG_W;
                    A[i] = ok ? ra[c] : 0.f;
                    B[i] = ok ? rb[c] : 0.f;
                }
            }
        } else {
#pragma unroll
            for (int i = 0; i < 20; ++i) { A[i] = 0.f; B[i] = 0.f; }
        }
        // output col W0+u uses taps A[3+u .. 13+u]
        float o1[4], o2[4], o11[4], o22[4], o12[4];
#pragma unroll
        for (int u = 0; u < 4; ++u) {
            float t1 = 0.f, t2 = 0.f, t11 = 0.f, t22 = 0.f, t12 = 0.f;
#pragma unroll
            for (int k = 0; k < NTAP; ++k) {
                const float gk = g[k];
                const float a = A[3 + u + k], b = B[3 + u + k];
                t1  += gk * a;
                t2  += gk * b;
                t11 += (gk * a) * a;
                t22 += (gk * b) * b;
                t12 += (gk * a) * b;
            }
            o1[u] = t1; o2[u] = t2; o11[u] = t11; o22[u] = t22; o12[u] = t12;
        }
        const int ho = r * SH + cg * 4;          // b64-aligned (SH even, cg*4 even)
        *(__half2*)&h1 [ho]     = __floats2half2_rn(o1 [0], o1 [1]);
        *(__half2*)&h1 [ho + 2] = __floats2half2_rn(o1 [2], o1 [3]);
        *(__half2*)&h2 [ho]     = __floats2half2_rn(o2 [0], o2 [1]);
        *(__half2*)&h2 [ho + 2] = __floats2half2_rn(o2 [2], o2 [3]);
        *(__half2*)&h11[ho]     = __floats2half2_rn(o11[0], o11[1]);
        *(__half2*)&h11[ho + 2] = __floats2half2_rn(o11[2], o11[3]);
        *(__half2*)&h22[ho]     = __floats2half2_rn(o22[0], o22[1]);
        *(__half2*)&h22[ho + 2] = __floats2half2_rn(o22[2], o22[3]);
        *(__half2*)&h12[ho]     = __floats2half2_rn(o12[0], o12[1]);
        *(__half2*)&h12[ho + 2] = __floats2half2_rn(o12[2], o12[3]);
    }
    __syncthreads();

    // ---- vertical pass: threads 0..127, each 4 cols x 4 rows, h-rows read once ----
    float local = 0.f;
    if (threadIdx.x < 128) {
        const int cg = threadIdx.x & 15;
        const int rg = threadIdx.x >> 4;
        const int c0 = cg * 4;
        const int r0 = rg * 4;
        float a1[4][4] = {}, a2[4][4] = {}, a11[4][4] = {}, a22[4][4] = {}, a12[4][4] = {};
#pragma unroll
        for (int j = 0; j < 14; ++j) {
            const int ho = (r0 + j) * SH + c0;
            const __half2* p1  = (const __half2*)&h1 [ho];
            const __half2* p2  = (const __half2*)&h2 [ho];
            const __half2* p11 = (const __half2*)&h11[ho];
            const __half2* p22 = (const __half2*)&h22[ho];
            const __half2* p12 = (const __half2*)&h12[ho];
            float f1[4], f2[4], f11[4], f22[4], f12[4];
            { float2 x = __half22float2(p1 [0]), y = __half22float2(p1 [1]);
              f1 [0]=x.x; f1 [1]=x.y; f1 [2]=y.x; f1 [3]=y.y; }
            { float2 x = __half22float2(p2 [0]), y = __half22float2(p2 [1]);
              f2 [0]=x.x; f2 [1]=x.y; f2 [2]=y.x; f2 [3]=y.y; }
            { float2 x = __half22float2(p11[0]), y = __half22float2(p11[1]);
              f11[0]=x.x; f11[1]=x.y; f11[2]=y.x; f11[3]=y.y; }
            { float2 x = __half22float2(p22[0]), y = __half22float2(p22[1]);
              f22[0]=x.x; f22[1]=x.y; f22[2]=y.x; f22[3]=y.y; }
            { float2 x = __half22float2(p12[0]), y = __half22float2(p12[1]);
              f12[0]=x.x; f12[1]=x.y; f12[2]=y.x; f12[3]=y.y; }
#pragma unroll
            for (int i = 0; i < 4; ++i) {
                if (j >= i && j <= i + 10) {
                    const float gk = g[j - i];
#pragma unroll
                    for (int c = 0; c < 4; ++c) {
                        a1 [i][c] += gk * f1 [c];
                        a2 [i][c] += gk * f2 [c];
                        a11[i][c] += gk * f11[c];
                        a22[i][c] += gk * f22[c];
                        a12[i][c] += gk * f12[c];
                    }
                }
            }
        }
#pragma unroll
        for (int i = 0; i < 4; ++i) {
#pragma unroll
            for (int c = 0; c < 4; ++c) {
                const float m1 = a1[i][c], m2 = a2[i][c];
                const float mu1s = m1 * m1, mu2s = m2 * m2, mu12 = m1 * m2;
                const float sg1  = a11[i][c] - mu1s;
                const float sg2  = a22[i][c] - mu2s;
                const float sg12 = a12[i][c] - mu12;
                const float num = (2.f * mu12 + C1) * (2.f * sg12 + C2);
                const float den = (mu1s + mu2s + C1) * (sg1 + sg2 + C2) + 1e-12f;
                local += num / den;
            }
        }
    }

    // ---- block reduction ----
#pragma unroll
    for (int off = 32; off > 0; off >>= 1)
        local += __shfl_down(local, off, 64);
    const int lane = threadIdx.x & 63, wave = threadIdx.x >> 6;
    if (lane == 0) wsums[wave] = local;
    __syncthreads();
    if (threadIdx.x == 0) {
        const double bsum = (double)(wsums[0] + wsums[1] + wsums[2] + wsums[3]);
        if (mode == 0) {
            const int bid = (blockIdx.z * NBLKY + blockIdx.y) * NBLKX + blockIdx.x;
            sink[bid] = bsum;
        } else {
            atomicAdd(sink, bsum);
        }
    }
}

__global__ __launch_bounds__(256) void ssim_finalize(const double* __restrict__ partial,
                                                     float* __restrict__ out, int count) {
    __shared__ double ws[4];
    double s = 0.0;
    for (int i = threadIdx.x; i < count; i += 256) s += partial[i];
#pragma unroll
    for (int off = 32; off > 0; off >>= 1)
        s += __shfl_down(s, off, 64);
    const int lane = threadIdx.x & 63, wave = threadIdx.x >> 6;
    if (lane == 0) ws[wave] = s;
    __syncthreads();
    if (threadIdx.x == 0) {
        const double tot = ws[0] + ws[1] + ws[2] + ws[3];
        const double n = (double)NBC * IMG_H * IMG_W;
        out[0] = (float)(1.0 - tot / n);
    }
}

extern "C" void kernel_launch(void* const* d_in, const int* in_sizes, int n_in,
                              void* d_out, int out_size, void* d_ws, size_t ws_size,
                              hipStream_t stream) {
    const float* sr = (const float*)d_in[0];
    const float* hr = (const float*)d_in[1];
    float* out = (float*)d_out;
    const dim3 grid(NBLKX, NBLKY, NBC);

    if (ws_size >= (size_t)NBLK * sizeof(double)) {
        double* partial = (double*)d_ws; // fully overwritten each call
        ssim_main<<<grid, dim3(256), 0, stream>>>(sr, hr, partial, 0);
        ssim_finalize<<<dim3(1), dim3(256), 0, stream>>>(partial, out, NBLK);
    } else {
        double* acc = (double*)d_ws;
        ssim_init<<<dim3(1), dim3(64), 0, stream>>>(acc);
        ssim_main<<<grid, dim3(256), 0, stream>>>(sr, hr, acc, 1);
        ssim_finalize<<<dim3(1), dim3(256), 0, stream>>>(acc, out, 1);
    }
}

// Round 4
// 184.029 us; speedup vs baseline: 2.3245x; 2.3245x over previous
//
#include <hip/hip_runtime.h>

// SSIM loss, fused, R4.
// R3 post-mortem: *(float4*)&local_array[] pointer-casts defeated SROA -> 20-float
// A/B arrays spilled to scratch (WRITE_SIZE 590MB, VGPR=64). R4 keeps R3's structure
// (no raw LDS tile, fp16 h-intermediates, single barrier) but:
//  - all local arrays written elementwise from named float4 temps (register-resident)
//  - LDS h-arrays are _Float16 with ext_vector<4> b64 access
//  - v-pass: 2 rows x 4 cols per thread -> all 256 threads active, 40 accumulators

typedef _Float16 f16;
typedef __attribute__((ext_vector_type(4))) _Float16 h4;

constexpr int IMG_H = 512;
constexpr int IMG_W = 512;
constexpr int NBC   = 48;             // B*C planes
constexpr int TW    = 64;             // output tile width
constexpr int TH    = 32;             // output tile height
constexpr int HALO  = 5;
constexpr int NTAP  = 11;
constexpr int IH    = TH + 2*HALO;    // 42 h-rows
constexpr int SH    = TW + 8;         // 72 halves = 144B = 36 banks (== 4 mod 32): <=2-way b64 aliasing
constexpr int NBLKX = IMG_W / TW;     // 8
constexpr int NBLKY = IMG_H / TH;     // 16
constexpr int NBLK  = NBLKX * NBLKY * NBC; // 6144
constexpr float C1 = 1.0e-4f;
constexpr float C2 = 9.0e-4f;

__device__ __forceinline__ void make_weights(float* g) {
    float gsum = 0.f;
#pragma unroll
    for (int i = 0; i < NTAP; ++i) {
        float d = (float)(i - HALO);
        g[i] = expf(-d * d / (2.0f * 1.5f * 1.5f));
        gsum += g[i];
    }
#pragma unroll
    for (int i = 0; i < NTAP; ++i) g[i] /= gsum;
}

__global__ __launch_bounds__(64) void ssim_init(double* acc) {
    if (threadIdx.x == 0) acc[0] = 0.0;
}

__global__ __launch_bounds__(256, 4) void ssim_main(const float* __restrict__ sr,
                                                    const float* __restrict__ hr,
                                                    double* __restrict__ sink,
                                                    int mode) {
    __shared__ f16 h1 [IH * SH];
    __shared__ f16 h2 [IH * SH];
    __shared__ f16 h11[IH * SH];
    __shared__ f16 h22[IH * SH];
    __shared__ f16 h12[IH * SH];
    __shared__ float wsums[4];

    float g[NTAP];
    make_weights(g);

    const int bc      = blockIdx.z;
    const int gr0     = blockIdx.y * TH - HALO;  // global row of h-row 0
    const int gc_base = blockIdx.x * TW;         // global col of output col 0
    const float* __restrict__ srp = sr + (size_t)bc * IMG_H * IMG_W;
    const float* __restrict__ hrp = hr + (size_t)bc * IMG_H * IMG_W;

    // ---- horizontal pass: task = 1 h-row x 4 output cols, direct global reads ----
    for (int tt = threadIdx.x; tt < IH * (TW / 4); tt += 256) { // 42*16 = 672
        const int r  = tt >> 4;
        const int cg = tt & 15;
        const int gr = gr0 + r;
        const int W0 = gc_base + cg * 4;         // first output col of this task
        float A[20], B[20];                      // global cols W0-8 .. W0+11 (registers!)
        if ((unsigned)gr < (unsigned)IMG_H) {
            const float* __restrict__ ra = srp + (size_t)gr * IMG_W;
            const float* __restrict__ rb = hrp + (size_t)gr * IMG_W;
            if (W0 >= 8 && W0 <= 500) {          // interior: 5 aligned float4 each
                const float4* pa = (const float4*)&ra[W0 - 8];
                const float4* pb = (const float4*)&rb[W0 - 8];
                const float4 a0 = pa[0], a1v = pa[1], a2v = pa[2], a3v = pa[3], a4v = pa[4];
                const float4 b0 = pb[0], b1v = pb[1], b2v = pb[2], b3v = pb[3], b4v = pb[4];
                A[0]=a0.x;  A[1]=a0.y;  A[2]=a0.z;  A[3]=a0.w;
                A[4]=a1v.x; A[5]=a1v.y; A[6]=a1v.z; A[7]=a1v.w;
                A[8]=a2v.x; A[9]=a2v.y; A[10]=a2v.z;A[11]=a2v.w;
                A[12]=a3v.x;A[13]=a3v.y;A[14]=a3v.z;A[15]=a3v.w;
                A[16]=a4v.x;A[17]=a4v.y;A[18]=a4v.z;A[19]=a4v.w;
                B[0]=b0.x;  B[1]=b0.y;  B[2]=b0.z;  B[3]=b0.w;
                B[4]=b1v.x; B[5]=b1v.y; B[6]=b1v.z; B[7]=b1v.w;
                B[8]=b2v.x; B[9]=b2v.y; B[10]=b2v.z;B[11]=b2v.w;
                B[12]=b3v.x;B[13]=b3v.y;B[14]=b3v.z;B[15]=b3v.w;
                B[16]=b4v.x;B[17]=b4v.y;B[18]=b4v.z;B[19]=b4v.w;
            } else {                             // image-edge columns: guarded scalar
#pragma unroll
                for (int i = 0; i < 20; ++i) {
                    const int c = W0 - 8 + i;
                    const bool ok = (unsigned)c < (unsigned)IMG_W;
                    A[i] = ok ? ra[c] : 0.f;
                    B[i] = ok ? rb[c] : 0.f;
                }
            }
        } else {
#pragma unroll
            for (int i = 0; i < 20; ++i) { A[i] = 0.f; B[i] = 0.f; }
        }
        // output col W0+u uses taps A[3+u .. 13+u]
        float o1[4], o2[4], o11[4], o22[4], o12[4];
#pragma unroll
        for (int u = 0; u < 4; ++u) {
            float t1 = 0.f, t2 = 0.f, t11 = 0.f, t22 = 0.f, t12 = 0.f;
#pragma unroll
            for (int k = 0; k < NTAP; ++k) {
                const float gk = g[k];
                const float a = A[3 + u + k], b = B[3 + u + k];
                const float ga = gk * a, gb = gk * b;
                t1  += ga;
                t2  += gb;
                t11 += ga * a;
                t22 += gb * b;
                t12 += ga * b;
            }
            o1[u] = t1; o2[u] = t2; o11[u] = t11; o22[u] = t22; o12[u] = t12;
        }
        const int ho = r * SH + cg * 4;          // multiple of 4 halves -> 8B aligned
        *(h4*)&h1 [ho] = (h4){(f16)o1 [0], (f16)o1 [1], (f16)o1 [2], (f16)o1 [3]};
        *(h4*)&h2 [ho] = (h4){(f16)o2 [0], (f16)o2 [1], (f16)o2 [2], (f16)o2 [3]};
        *(h4*)&h11[ho] = (h4){(f16)o11[0], (f16)o11[1], (f16)o11[2], (f16)o11[3]};
        *(h4*)&h22[ho] = (h4){(f16)o22[0], (f16)o22[1], (f16)o22[2], (f16)o22[3]};
        *(h4*)&h12[ho] = (h4){(f16)o12[0], (f16)o12[1], (f16)o12[2], (f16)o12[3]};
    }
    __syncthreads();

    // ---- vertical pass: 256 threads, each 2 rows x 4 cols; h-rows read once ----
    float local = 0.f;
    {
        const int cg = threadIdx.x & 15;         // 16 col groups x 4 cols
        const int rg = threadIdx.x >> 4;         // 16 row groups x 2 rows
        const int c0 = cg * 4;
        const int r0 = rg * 2;
        float a1[2][4] = {}, a2[2][4] = {}, a11[2][4] = {}, a22[2][4] = {}, a12[2][4] = {};
#pragma unroll
        for (int j = 0; j < 12; ++j) {           // h-rows r0 .. r0+11
            const int ho = (r0 + j) * SH + c0;
            const h4 x1  = *(const h4*)&h1 [ho];
            const h4 x2  = *(const h4*)&h2 [ho];
            const h4 x11 = *(const h4*)&h11[ho];
            const h4 x22 = *(const h4*)&h22[ho];
            const h4 x12 = *(const h4*)&h12[ho];
            float f1[4], f2[4], f11[4], f22[4], f12[4];
            f1 [0] = (float)x1.x;  f1 [1] = (float)x1.y;  f1 [2] = (float)x1.z;  f1 [3] = (float)x1.w;
            f2 [0] = (float)x2.x;  f2 [1] = (float)x2.y;  f2 [2] = (float)x2.z;  f2 [3] = (float)x2.w;
            f11[0] = (float)x11.x; f11[1] = (float)x11.y; f11[2] = (float)x11.z; f11[3] = (float)x11.w;
            f22[0] = (float)x22.x; f22[1] = (float)x22.y; f22[2] = (float)x22.z; f22[3] = (float)x22.w;
            f12[0] = (float)x12.x; f12[1] = (float)x12.y; f12[2] = (float)x12.z; f12[3] = (float)x12.w;
#pragma unroll
            for (int i = 0; i < 2; ++i) {
                if (j >= i && j <= i + 10) {
                    const float gk = g[j - i];
#pragma unroll
                    for (int c = 0; c < 4; ++c) {
                        a1 [i][c] += gk * f1 [c];
                        a2 [i][c] += gk * f2 [c];
                        a11[i][c] += gk * f11[c];
                        a22[i][c] += gk * f22[c];
                        a12[i][c] += gk * f12[c];
                    }
                }
            }
        }
#pragma unroll
        for (int i = 0; i < 2; ++i) {
#pragma unroll
            for (int c = 0; c < 4; ++c) {
                const float m1 = a1[i][c], m2 = a2[i][c];
                const float mu1s = m1 * m1, mu2s = m2 * m2, mu12 = m1 * m2;
                const float sg1  = a11[i][c] - mu1s;
                const float sg2  = a22[i][c] - mu2s;
                const float sg12 = a12[i][c] - mu12;
                const float num = (2.f * mu12 + C1) * (2.f * sg12 + C2);
                const float den = (mu1s + mu2s + C1) * (sg1 + sg2 + C2) + 1e-12f;
                local += num / den;
            }
        }
    }

    // ---- block reduction ----
#pragma unroll
    for (int off = 32; off > 0; off >>= 1)
        local += __shfl_down(local, off, 64);
    const int lane = threadIdx.x & 63, wave = threadIdx.x >> 6;
    if (lane == 0) wsums[wave] = local;
    __syncthreads();
    if (threadIdx.x == 0) {
        const double bsum = (double)(wsums[0] + wsums[1] + wsums[2] + wsums[3]);
        if (mode == 0) {
            const int bid = (blockIdx.z * NBLKY + blockIdx.y) * NBLKX + blockIdx.x;
            sink[bid] = bsum;
        } else {
            atomicAdd(sink, bsum);
        }
    }
}

__global__ __launch_bounds__(256) void ssim_finalize(const double* __restrict__ partial,
                                                     float* __restrict__ out, int count) {
    __shared__ double ws[4];
    double s = 0.0;
    for (int i = threadIdx.x; i < count; i += 256) s += partial[i];
#pragma unroll
    for (int off = 32; off > 0; off >>= 1)
        s += __shfl_down(s, off, 64);
    const int lane = threadIdx.x & 63, wave = threadIdx.x >> 6;
    if (lane == 0) ws[wave] = s;
    __syncthreads();
    if (threadIdx.x == 0) {
        const double tot = ws[0] + ws[1] + ws[2] + ws[3];
        const double n = (double)NBC * IMG_H * IMG_W;
        out[0] = (float)(1.0 - tot / n);
    }
}

extern "C" void kernel_launch(void* const* d_in, const int* in_sizes, int n_in,
                              void* d_out, int out_size, void* d_ws, size_t ws_size,
                              hipStream_t stream) {
    const float* sr = (const float*)d_in[0];
    const float* hr = (const float*)d_in[1];
    float* out = (float*)d_out;
    const dim3 grid(NBLKX, NBLKY, NBC);

    if (ws_size >= (size_t)NBLK * sizeof(double)) {
        double* partial = (double*)d_ws; // fully overwritten each call
        ssim_main<<<grid, dim3(256), 0, stream>>>(sr, hr, partial, 0);
        ssim_finalize<<<dim3(1), dim3(256), 0, stream>>>(partial, out, NBLK);
    } else {
        double* acc = (double*)d_ws;
        ssim_init<<<dim3(1), dim3(64), 0, stream>>>(acc);
        ssim_main<<<grid, dim3(256), 0, stream>>>(sr, hr, acc, 1);
        ssim_finalize<<<dim3(1), dim3(256), 0, stream>>>(acc, out, 1);
    }
}

// Round 6
// 179.806 us; speedup vs baseline: 2.3791x; 1.0235x over previous
//
#include <hip/hip_runtime.h>

// SSIM loss, fused, R6 (= R5 with the __fp16/_Float16 vector type mismatch fixed:
// __builtin_amdgcn_cvt_pkrtz returns __fp16 ext_vector_type(2), so all half
// storage/vector types are __fp16 now).
// R4 post-mortem: VALU-issue bound (VALUBusy 60%, HBM 13%, conflicts ~0).
// R5/R6: packed fp32 math (v_pk_fma_f32 via float ext_vector_type(2)) in both
// passes, packed f32->f16 stores (cvt_pkrtz), rcp instead of precise div.
// Structure: direct global h-pass reads, fp16 h-arrays in LDS (30.3KB ->
// 4 blocks/CU), single barrier, per-block partials.

typedef float f32x2 __attribute__((ext_vector_type(2)));
typedef __fp16 f16;
typedef __attribute__((ext_vector_type(4))) __fp16 h4;
typedef __attribute__((ext_vector_type(2))) __fp16 h2v;

constexpr int IMG_H = 512;
constexpr int IMG_W = 512;
constexpr int NBC   = 48;             // B*C planes
constexpr int TW    = 64;             // output tile width
constexpr int TH    = 32;             // output tile height
constexpr int HALO  = 5;
constexpr int NTAP  = 11;
constexpr int IH    = TH + 2*HALO;    // 42 h-rows
constexpr int SH    = TW + 8;         // 72 halves/row: bank-benign, b64-aligned
constexpr int NBLKX = IMG_W / TW;     // 8
constexpr int NBLKY = IMG_H / TH;     // 16
constexpr int NBLK  = NBLKX * NBLKY * NBC; // 6144
constexpr float C1 = 1.0e-4f;
constexpr float C2 = 9.0e-4f;

__device__ __forceinline__ void make_weights(float* g) {
    float gsum = 0.f;
#pragma unroll
    for (int i = 0; i < NTAP; ++i) {
        float d = (float)(i - HALO);
        g[i] = expf(-d * d / (2.0f * 1.5f * 1.5f));
        gsum += g[i];
    }
#pragma unroll
    for (int i = 0; i < NTAP; ++i) g[i] /= gsum;
}

__global__ __launch_bounds__(64) void ssim_init(double* acc) {
    if (threadIdx.x == 0) acc[0] = 0.0;
}

__global__ __launch_bounds__(256, 4) void ssim_main(const float* __restrict__ sr,
                                                    const float* __restrict__ hr,
                                                    double* __restrict__ sink,
                                                    int mode) {
    __shared__ f16 h1 [IH * SH];
    __shared__ f16 h2 [IH * SH];
    __shared__ f16 h11[IH * SH];
    __shared__ f16 h22[IH * SH];
    __shared__ f16 h12[IH * SH];
    __shared__ float wsums[4];

    float g[NTAP];
    make_weights(g);

    const int bc      = blockIdx.z;
    const int gr0     = blockIdx.y * TH - HALO;  // global row of h-row 0
    const int gc_base = blockIdx.x * TW;         // global col of output col 0
    const float* __restrict__ srp = sr + (size_t)bc * IMG_H * IMG_W;
    const float* __restrict__ hrp = hr + (size_t)bc * IMG_H * IMG_W;

    // ---- horizontal pass: task = 1 h-row x 4 output cols ----
    for (int tt = threadIdx.x; tt < IH * (TW / 4); tt += 256) { // 42*16 = 672
        const int r  = tt >> 4;
        const int cg = tt & 15;
        const int gr = gr0 + r;
        const int W0 = gc_base + cg * 4;         // first output col of this task
        f32x2 AB[20];                            // (sr,hr) pairs, cols W0-8 .. W0+11
        if ((unsigned)gr < (unsigned)IMG_H) {
            const float* __restrict__ ra = srp + (size_t)gr * IMG_W;
            const float* __restrict__ rb = hrp + (size_t)gr * IMG_W;
            if (W0 >= 8 && W0 <= 500) {          // interior: 5 aligned float4 each
                const float4* pa = (const float4*)&ra[W0 - 8];
                const float4* pb = (const float4*)&rb[W0 - 8];
                const float4 a0 = pa[0], a1v = pa[1], a2v = pa[2], a3v = pa[3], a4v = pa[4];
                const float4 b0 = pb[0], b1v = pb[1], b2v = pb[2], b3v = pb[3], b4v = pb[4];
                AB[0]  = (f32x2){a0.x,  b0.x};  AB[1]  = (f32x2){a0.y,  b0.y};
                AB[2]  = (f32x2){a0.z,  b0.z};  AB[3]  = (f32x2){a0.w,  b0.w};
                AB[4]  = (f32x2){a1v.x, b1v.x}; AB[5]  = (f32x2){a1v.y, b1v.y};
                AB[6]  = (f32x2){a1v.z, b1v.z}; AB[7]  = (f32x2){a1v.w, b1v.w};
                AB[8]  = (f32x2){a2v.x, b2v.x}; AB[9]  = (f32x2){a2v.y, b2v.y};
                AB[10] = (f32x2){a2v.z, b2v.z}; AB[11] = (f32x2){a2v.w, b2v.w};
                AB[12] = (f32x2){a3v.x, b3v.x}; AB[13] = (f32x2){a3v.y, b3v.y};
                AB[14] = (f32x2){a3v.z, b3v.z}; AB[15] = (f32x2){a3v.w, b3v.w};
                AB[16] = (f32x2){a4v.x, b4v.x}; AB[17] = (f32x2){a4v.y, b4v.y};
                AB[18] = (f32x2){a4v.z, b4v.z}; AB[19] = (f32x2){a4v.w, b4v.w};
            } else {                             // image-edge cols: guarded scalar
#pragma unroll
                for (int i = 0; i < 20; ++i) {
                    const int c = W0 - 8 + i;
                    const bool ok = (unsigned)c < (unsigned)IMG_W;
                    AB[i] = ok ? (f32x2){ra[c], rb[c]} : (f32x2){0.f, 0.f};
                }
            }
        } else {
#pragma unroll
            for (int i = 0; i < 20; ++i) AB[i] = (f32x2){0.f, 0.f};
        }
        // output col W0+u uses taps AB[3+u .. 13+u]; process u in pairs
#pragma unroll
        for (int up = 0; up < 2; ++up) {
            f32x2 sm0 = {0.f, 0.f}, sq0 = {0.f, 0.f};
            f32x2 sm1 = {0.f, 0.f}, sq1 = {0.f, 0.f};
            float sp0 = 0.f, sp1 = 0.f;
#pragma unroll
            for (int k = 0; k < NTAP; ++k) {
                const f32x2 g2 = {g[k], g[k]};
                const f32x2 x0 = AB[3 + 2*up + k];
                const f32x2 x1 = AB[4 + 2*up + k];
                const f32x2 ga0 = g2 * x0;       // pk_mul: (g*a, g*b)
                const f32x2 ga1 = g2 * x1;
                sm0 += ga0;                      // pk_add
                sm1 += ga1;
                sq0 += ga0 * x0;                 // pk_fma: (g*a*a, g*b*b)
                sq1 += ga1 * x1;
                sp0 += ga0.x * x0.y;             // fma: g*a*b
                sp1 += ga1.x * x1.y;
            }
            const int ho = r * SH + cg * 4 + 2 * up;
            *(h2v*)&h1 [ho] = __builtin_amdgcn_cvt_pkrtz(sm0.x, sm1.x);
            *(h2v*)&h2 [ho] = __builtin_amdgcn_cvt_pkrtz(sm0.y, sm1.y);
            *(h2v*)&h11[ho] = __builtin_amdgcn_cvt_pkrtz(sq0.x, sq1.x);
            *(h2v*)&h22[ho] = __builtin_amdgcn_cvt_pkrtz(sq0.y, sq1.y);
            *(h2v*)&h12[ho] = __builtin_amdgcn_cvt_pkrtz(sp0,   sp1);
        }
    }
    __syncthreads();

    // ---- vertical pass: 256 threads, each 2 rows x 4 cols; packed accumulation ----
    float local = 0.f;
    {
        const int cg = threadIdx.x & 15;
        const int rg = threadIdx.x >> 4;
        const int c0 = cg * 4;
        const int r0 = rg * 2;
        f32x2 am1[2][2] = {}, am2[2][2] = {}, aq1[2][2] = {}, aq2[2][2] = {}, ap[2][2] = {};
#pragma unroll
        for (int j = 0; j < 12; ++j) {           // h-rows r0 .. r0+11
            const int ho = (r0 + j) * SH + c0;
            const h4 x1  = *(const h4*)&h1 [ho];
            const h4 x2  = *(const h4*)&h2 [ho];
            const h4 x11 = *(const h4*)&h11[ho];
            const h4 x22 = *(const h4*)&h22[ho];
            const h4 x12 = *(const h4*)&h12[ho];
            const f32x2 v1l  = {(float)x1.x,  (float)x1.y},  v1h  = {(float)x1.z,  (float)x1.w};
            const f32x2 v2l  = {(float)x2.x,  (float)x2.y},  v2h  = {(float)x2.z,  (float)x2.w};
            const f32x2 q1l  = {(float)x11.x, (float)x11.y}, q1h  = {(float)x11.z, (float)x11.w};
            const f32x2 q2l  = {(float)x22.x, (float)x22.y}, q2h  = {(float)x22.z, (float)x22.w};
            const f32x2 vpl  = {(float)x12.x, (float)x12.y}, vph  = {(float)x12.z, (float)x12.w};
#pragma unroll
            for (int i = 0; i < 2; ++i) {
                if (j >= i && j <= i + 10) {
                    const float gk = g[j - i];
                    const f32x2 g2 = {gk, gk};
                    am1[i][0] += g2 * v1l; am1[i][1] += g2 * v1h;
                    am2[i][0] += g2 * v2l; am2[i][1] += g2 * v2h;
                    aq1[i][0] += g2 * q1l; aq1[i][1] += g2 * q1h;
                    aq2[i][0] += g2 * q2l; aq2[i][1] += g2 * q2h;
                    ap [i][0] += g2 * vpl; ap [i][1] += g2 * vph;
                }
            }
        }
#pragma unroll
        for (int i = 0; i < 2; ++i) {
#pragma unroll
            for (int p = 0; p < 2; ++p) {
                const f32x2 m1 = am1[i][p], m2 = am2[i][p];
                const f32x2 mu1s = m1 * m1, mu2s = m2 * m2, mu12 = m1 * m2;
                const f32x2 sg1  = aq1[i][p] - mu1s;
                const f32x2 sg2  = aq2[i][p] - mu2s;
                const f32x2 sg12 = ap [i][p] - mu12;
                const f32x2 num = (2.f * mu12 + C1) * (2.f * sg12 + C2);
                const f32x2 den = (mu1s + mu2s + C1) * (sg1 + sg2 + C2) + 1e-12f;
                local += num.x * __builtin_amdgcn_rcpf(den.x);
                local += num.y * __builtin_amdgcn_rcpf(den.y);
            }
        }
    }

    // ---- block reduction ----
#pragma unroll
    for (int off = 32; off > 0; off >>= 1)
        local += __shfl_down(local, off, 64);
    const int lane = threadIdx.x & 63, wave = threadIdx.x >> 6;
    if (lane == 0) wsums[wave] = local;
    __syncthreads();
    if (threadIdx.x == 0) {
        const double bsum = (double)(wsums[0] + wsums[1] + wsums[2] + wsums[3]);
        if (mode == 0) {
            const int bid = (blockIdx.z * NBLKY + blockIdx.y) * NBLKX + blockIdx.x;
            sink[bid] = bsum;
        } else {
            atomicAdd(sink, bsum);
        }
    }
}

__global__ __launch_bounds__(256) void ssim_finalize(const double* __restrict__ partial,
                                                     float* __restrict__ out, int count) {
    __shared__ double ws[4];
    double s = 0.0;
    for (int i = threadIdx.x; i < count; i += 256) s += partial[i];
#pragma unroll
    for (int off = 32; off > 0; off >>= 1)
        s += __shfl_down(s, off, 64);
    const int lane = threadIdx.x & 63, wave = threadIdx.x >> 6;
    if (lane == 0) ws[wave] = s;
    __syncthreads();
    if (threadIdx.x == 0) {
        const double tot = ws[0] + ws[1] + ws[2] + ws[3];
        const double n = (double)NBC * IMG_H * IMG_W;
        out[0] = (float)(1.0 - tot / n);
    }
}

extern "C" void kernel_launch(void* const* d_in, const int* in_sizes, int n_in,
                              void* d_out, int out_size, void* d_ws, size_t ws_size,
                              hipStream_t stream) {
    const float* sr = (const float*)d_in[0];
    const float* hr = (const float*)d_in[1];
    float* out = (float*)d_out;
    const dim3 grid(NBLKX, NBLKY, NBC);

    if (ws_size >= (size_t)NBLK * sizeof(double)) {
        double* partial = (double*)d_ws; // fully overwritten each call
        ssim_main<<<grid, dim3(256), 0, stream>>>(sr, hr, partial, 0);
        ssim_finalize<<<dim3(1), dim3(256), 0, stream>>>(partial, out, NBLK);
    } else {
        double* acc = (double*)d_ws;
        ssim_init<<<dim3(1), dim3(64), 0, stream>>>(acc);
        ssim_main<<<grid, dim3(256), 0, stream>>>(sr, hr, acc, 1);
        ssim_finalize<<<dim3(1), dim3(256), 0, stream>>>(acc, out, 1);
    }
}